// Round 1
// baseline (2904.875 us; speedup 1.0000x reference)
//
#include <hip/hip_runtime.h>

#define N_NODES 50000
#define N_EDGES 800000
#define D 128
#define NB 16  // nodes per GEMM block

// ---------------- degree histogram ----------------
__global__ void deg_kernel(const int* __restrict__ src, const int* __restrict__ dst,
                           float* __restrict__ deg_out, float* __restrict__ deg_in, int nE) {
    int e = blockIdx.x * blockDim.x + threadIdx.x;
    if (e < nE) {
        atomicAdd(&deg_out[src[e]], 1.0f);
        atomicAdd(&deg_in[dst[e]], 1.0f);
    }
}

// in-place deg -> rsqrt(max(deg,1))
__global__ void rsqrt_kernel(float* __restrict__ a, float* __restrict__ b, int n) {
    int i = blockIdx.x * blockDim.x + threadIdx.x;
    if (i < n) {
        a[i] = rsqrtf(fmaxf(a[i], 1.0f));
        b[i] = rsqrtf(fmaxf(b[i], 1.0f));
    }
}

// ---------------- edge aggregation (scatter-add) ----------------
// one thread per (edge, float4 chunk); 32 chunks per edge
__global__ void agg_kernel(const float4* __restrict__ xin, const int* __restrict__ src,
                           const int* __restrict__ dst, const float* __restrict__ scale,
                           float* __restrict__ msg, int nE) {
    int t = blockIdx.x * blockDim.x + threadIdx.x;
    int e = t >> 5;
    int c = t & 31;
    if (e >= nE) return;
    int s = src[e];
    int d = dst[e];
    float4 v = xin[(size_t)s * 32 + c];
    float sc = scale ? scale[s] : 1.0f;
    float* p = msg + (size_t)d * D + c * 4;
    atomicAdd(p + 0, v.x * sc);
    atomicAdd(p + 1, v.y * sc);
    atomicAdd(p + 2, v.z * sc);
    atomicAdd(p + 3, v.w * sc);
}

// ---------------- per-node dense layer ----------------
// out[n][j] = f( (msg[n][:] * rs_in[n]) @ W[:,j] + bias[j] )
// RELU_OUTSCALE: f(v) = relu(v) * rs_out[n]  (pre-normalize for next layer's agg)
template <bool RELU_OUTSCALE>
__global__ void gemm_kernel(const float* __restrict__ msg, const float* __restrict__ rs_in,
                            const float* __restrict__ rs_out, const float* __restrict__ W,
                            const float* __restrict__ bias, float* __restrict__ out, int nN) {
    __shared__ float s[NB * D];
    int tid = threadIdx.x;  // 0..127
    int n0 = blockIdx.x * NB;
#pragma unroll
    for (int n = 0; n < NB; n++) {
        int node = n0 + n;
        s[n * D + tid] = (node < nN) ? msg[(size_t)node * D + tid] * rs_in[node] : 0.0f;
    }
    __syncthreads();
    float acc[NB];
#pragma unroll
    for (int n = 0; n < NB; n++) acc[n] = 0.0f;
    for (int k = 0; k < D; k++) {
        float w = W[k * D + tid];
#pragma unroll
        for (int n = 0; n < NB; n++) acc[n] += s[n * D + k] * w;
    }
    float bj = bias[tid];
#pragma unroll
    for (int n = 0; n < NB; n++) {
        int node = n0 + n;
        if (node >= nN) break;
        float v = acc[n] + bj;
        if (RELU_OUTSCALE) v = fmaxf(v, 0.0f) * rs_out[node];
        out[(size_t)node * D + tid] = v;
    }
}

extern "C" void kernel_launch(void* const* d_in, const int* in_sizes, int n_in,
                              void* d_out, int out_size, void* d_ws, size_t ws_size,
                              hipStream_t stream) {
    const float* x   = (const float*)d_in[0];
    const int*   src = (const int*)d_in[1];
    const int*   dst = (const int*)d_in[2];
    const float* W1  = (const float*)d_in[3];
    const float* b1  = (const float*)d_in[4];
    const float* W2  = (const float*)d_in[5];
    const float* b2  = (const float*)d_in[6];
    float* out = (float*)d_out;

    // workspace layout (floats)
    float* ws = (float*)d_ws;
    float* rs_out = ws;                    // 50000 (deg_out -> rsqrt in place)
    float* rs_in  = ws + N_NODES;          // 50000
    float* msg    = ws + 2 * N_NODES;      // 50000*128
    float* hs     = msg + (size_t)N_NODES * D;  // 50000*128

    // zero degree counters + msg buffer
    hipMemsetAsync(rs_out, 0, 2 * N_NODES * sizeof(float), stream);
    hipMemsetAsync(msg, 0, (size_t)N_NODES * D * sizeof(float), stream);

    // degrees
    deg_kernel<<<(N_EDGES + 255) / 256, 256, 0, stream>>>(src, dst, rs_out, rs_in, N_EDGES);
    rsqrt_kernel<<<(N_NODES + 255) / 256, 256, 0, stream>>>(rs_out, rs_in, N_NODES);

    // layer 1 aggregation: msg[dst] += x[src] * rs_out[src]
    {
        long long threads = (long long)N_EDGES * 32;
        int blocks = (int)((threads + 255) / 256);
        agg_kernel<<<blocks, 256, 0, stream>>>((const float4*)x, src, dst, rs_out, msg, N_EDGES);
    }

    // layer 1 dense: hs = relu((msg * rs_in) @ W1 + b1) * rs_out
    gemm_kernel<true><<<(N_NODES + NB - 1) / NB, D, 0, stream>>>(msg, rs_in, rs_out, W1, b1, hs, N_NODES);

    // layer 2 aggregation: msg[dst] += hs[src]  (hs already pre-scaled by rs_out)
    hipMemsetAsync(msg, 0, (size_t)N_NODES * D * sizeof(float), stream);
    {
        long long threads = (long long)N_EDGES * 32;
        int blocks = (int)((threads + 255) / 256);
        agg_kernel<<<blocks, 256, 0, stream>>>((const float4*)hs, src, dst, nullptr, msg, N_EDGES);
    }

    // layer 2 dense: out = (msg * rs_in) @ W2 + b2
    gemm_kernel<false><<<(N_NODES + NB - 1) / NB, D, 0, stream>>>(msg, rs_in, nullptr, W2, b2, out, N_NODES);
}

// Round 2
// 539.848 us; speedup vs baseline: 5.3809x; 5.3809x over previous
//
#include <hip/hip_runtime.h>

#define N_NODES 50000
#define N_EDGES 800000
#define D 128
#define NB 16     // nodes per GEMM block
#define SCAN_T 1024

// ---------------- degree + CSR histogram ----------------
__global__ void deg_kernel(const int* __restrict__ src, const int* __restrict__ dst,
                           float* __restrict__ deg_out, float* __restrict__ deg_in,
                           int* __restrict__ csr_cnt, int nE) {
    int e = blockIdx.x * blockDim.x + threadIdx.x;
    if (e < nE) {
        atomicAdd(&deg_out[src[e]], 1.0f);
        int d = dst[e];
        atomicAdd(&deg_in[d], 1.0f);
        atomicAdd(&csr_cnt[d], 1);
    }
}

// in-place deg -> rsqrt(max(deg,1))
__global__ void rsqrt_kernel(float* __restrict__ a, float* __restrict__ b, int n) {
    int i = blockIdx.x * blockDim.x + threadIdx.x;
    if (i < n) {
        a[i] = rsqrtf(fmaxf(a[i], 1.0f));
        b[i] = rsqrtf(fmaxf(b[i], 1.0f));
    }
}

// ---------------- exclusive prefix scan (single block) ----------------
__global__ void scan_kernel(const int* __restrict__ cnt, int* __restrict__ off, int n) {
    __shared__ int part[SCAN_T];
    int tid = threadIdx.x;
    int chunk = (n + SCAN_T - 1) / SCAN_T;
    int beg = tid * chunk;
    int end = min(beg + chunk, n);
    int s = 0;
    for (int i = beg; i < end; i++) s += cnt[i];
    part[tid] = s;
    __syncthreads();
    // Hillis-Steele inclusive scan of partials
    for (int d = 1; d < SCAN_T; d <<= 1) {
        int v = (tid >= d) ? part[tid - d] : 0;
        __syncthreads();
        part[tid] += v;
        __syncthreads();
    }
    int run = part[tid] - s;  // exclusive base for this chunk
    for (int i = beg; i < end; i++) { off[i] = run; run += cnt[i]; }
    if (tid == SCAN_T - 1) off[n] = run;
}

// ---------------- scatter edges into CSR (sorted by dst) ----------------
__global__ void scatter_kernel(const int* __restrict__ src, const int* __restrict__ dst,
                               const int* __restrict__ off, int* __restrict__ cursor,
                               int* __restrict__ csr_src, int nE) {
    int e = blockIdx.x * blockDim.x + threadIdx.x;
    if (e < nE) {
        int d = dst[e];
        int pos = atomicAdd(&cursor[d], 1);
        csr_src[off[d] + pos] = src[e];
    }
}

// ---------------- gather aggregation (no feature atomics) ----------------
// 32 threads per dst node (float4 lanes), 8 nodes per 256-thread block.
// msg[n] = sum over incident edges of xin[s] * (scale ? scale[s] : 1)
__global__ void gather_kernel(const float4* __restrict__ xin, const int* __restrict__ off,
                              const int* __restrict__ csr_src, const float* __restrict__ scale,
                              float4* __restrict__ msg, int nN) {
    int node = blockIdx.x * 8 + (threadIdx.x >> 5);
    int c = threadIdx.x & 31;
    if (node >= nN) return;
    int beg = off[node], end = off[node + 1];
    float4 acc = make_float4(0.f, 0.f, 0.f, 0.f);
    for (int e = beg; e < end; e++) {
        int s = csr_src[e];
        float4 v = xin[(size_t)s * 32 + c];
        float sc = scale ? scale[s] : 1.0f;
        acc.x += v.x * sc;
        acc.y += v.y * sc;
        acc.z += v.z * sc;
        acc.w += v.w * sc;
    }
    msg[(size_t)node * 32 + c] = acc;
}

// ---------------- per-node dense layer ----------------
template <bool RELU_OUTSCALE>
__global__ void gemm_kernel(const float* __restrict__ msg, const float* __restrict__ rs_in,
                            const float* __restrict__ rs_out, const float* __restrict__ W,
                            const float* __restrict__ bias, float* __restrict__ out, int nN) {
    __shared__ float s[NB * D];
    int tid = threadIdx.x;  // 0..127
    int n0 = blockIdx.x * NB;
#pragma unroll
    for (int n = 0; n < NB; n++) {
        int node = n0 + n;
        s[n * D + tid] = (node < nN) ? msg[(size_t)node * D + tid] * rs_in[node] : 0.0f;
    }
    __syncthreads();
    float acc[NB];
#pragma unroll
    for (int n = 0; n < NB; n++) acc[n] = 0.0f;
    for (int k = 0; k < D; k++) {
        float w = W[k * D + tid];
#pragma unroll
        for (int n = 0; n < NB; n++) acc[n] += s[n * D + k] * w;
    }
    float bj = bias[tid];
#pragma unroll
    for (int n = 0; n < NB; n++) {
        int node = n0 + n;
        if (node >= nN) break;
        float v = acc[n] + bj;
        if (RELU_OUTSCALE) v = fmaxf(v, 0.0f) * rs_out[node];
        out[(size_t)node * D + tid] = v;
    }
}

extern "C" void kernel_launch(void* const* d_in, const int* in_sizes, int n_in,
                              void* d_out, int out_size, void* d_ws, size_t ws_size,
                              hipStream_t stream) {
    const float* x   = (const float*)d_in[0];
    const int*   src = (const int*)d_in[1];
    const int*   dst = (const int*)d_in[2];
    const float* W1  = (const float*)d_in[3];
    const float* b1  = (const float*)d_in[4];
    const float* W2  = (const float*)d_in[5];
    const float* b2  = (const float*)d_in[6];
    float* out = (float*)d_out;

    // workspace layout
    char* ws = (char*)d_ws;
    float* rs_out  = (float*)ws;                       ws += N_NODES * sizeof(float);
    float* rs_in   = (float*)ws;                       ws += N_NODES * sizeof(float);
    int*   csr_cnt = (int*)ws;                         ws += N_NODES * sizeof(int);
    int*   csr_off = (int*)ws;                         ws += (N_NODES + 1) * sizeof(int);
    int*   cursor  = (int*)ws;                         ws += N_NODES * sizeof(int);
    int*   csr_src = (int*)ws;                         ws += N_EDGES * sizeof(int);
    float* msg     = (float*)ws;                       ws += (size_t)N_NODES * D * sizeof(float);
    float* hs      = (float*)ws;                       ws += (size_t)N_NODES * D * sizeof(float);

    // zero degree counters / csr counters / cursor
    hipMemsetAsync(rs_out, 0, 2 * N_NODES * sizeof(float), stream);
    hipMemsetAsync(csr_cnt, 0, N_NODES * sizeof(int), stream);
    hipMemsetAsync(cursor, 0, N_NODES * sizeof(int), stream);

    // degrees + dst histogram
    deg_kernel<<<(N_EDGES + 255) / 256, 256, 0, stream>>>(src, dst, rs_out, rs_in, csr_cnt, N_EDGES);
    rsqrt_kernel<<<(N_NODES + 255) / 256, 256, 0, stream>>>(rs_out, rs_in, N_NODES);

    // CSR build
    scan_kernel<<<1, SCAN_T, 0, stream>>>(csr_cnt, csr_off, N_NODES);
    scatter_kernel<<<(N_EDGES + 255) / 256, 256, 0, stream>>>(src, dst, csr_off, cursor, csr_src, N_EDGES);

    // layer 1 aggregation: msg[n] = sum x[s] * rs_out[s]
    gather_kernel<<<(N_NODES + 7) / 8, 256, 0, stream>>>((const float4*)x, csr_off, csr_src, rs_out, (float4*)msg, N_NODES);

    // layer 1 dense: hs = relu((msg * rs_in) @ W1 + b1) * rs_out  (pre-scaled for next agg)
    gemm_kernel<true><<<(N_NODES + NB - 1) / NB, D, 0, stream>>>(msg, rs_in, rs_out, W1, b1, hs, N_NODES);

    // layer 2 aggregation: msg[n] = sum hs[s]
    gather_kernel<<<(N_NODES + 7) / 8, 256, 0, stream>>>((const float4*)hs, csr_off, csr_src, nullptr, (float4*)msg, N_NODES);

    // layer 2 dense: out = (msg * rs_in) @ W2 + b2
    gemm_kernel<false><<<(N_NODES + NB - 1) / NB, D, 0, stream>>>(msg, rs_in, nullptr, W2, b2, out, N_NODES);
}

// Round 3
// 497.298 us; speedup vs baseline: 5.8413x; 1.0856x over previous
//
#include <hip/hip_runtime.h>

#define N_NODES 50000
#define N_EDGES 800000
#define D 128
#define NB 16     // nodes per GEMM block
#define SCAN_T 1024

// ---------------- degree histograms (2 int atomics / edge) ----------------
__global__ void deg_kernel(const int* __restrict__ src, const int* __restrict__ dst,
                           int* __restrict__ cnt_src, int* __restrict__ cnt_dst, int nE) {
    int e = blockIdx.x * blockDim.x + threadIdx.x;
    if (e < nE) {
        atomicAdd(&cnt_src[src[e]], 1);
        atomicAdd(&cnt_dst[dst[e]], 1);
    }
}

// ---------------- exclusive prefix scan of cnt_dst (single block) ----------------
__global__ void scan_kernel(const int* __restrict__ cnt, int* __restrict__ off, int n) {
    __shared__ int part[SCAN_T];
    int tid = threadIdx.x;
    int chunk = (n + SCAN_T - 1) / SCAN_T;
    int beg = tid * chunk;
    int end = min(beg + chunk, n);
    int s = 0;
    for (int i = beg; i < end; i++) s += cnt[i];
    part[tid] = s;
    __syncthreads();
    for (int d = 1; d < SCAN_T; d <<= 1) {
        int v = (tid >= d) ? part[tid - d] : 0;
        __syncthreads();
        part[tid] += v;
        __syncthreads();
    }
    int run = part[tid] - s;  // exclusive base for this chunk
    for (int i = beg; i < end; i++) { off[i] = run; run += cnt[i]; }
    if (tid == SCAN_T - 1) off[n] = run;
}

// ---------------- fused: rs arrays, cursor init, xs = x * rs_out ----------------
// 256 threads = 8 nodes x 32 float4-lanes
__global__ void prescale_kernel(const float4* __restrict__ x, const int* __restrict__ cnt_src,
                                const int* __restrict__ cnt_dst, const int* __restrict__ off,
                                float* __restrict__ rs_out, float* __restrict__ rs_in,
                                int* __restrict__ cursor, float4* __restrict__ xs, int nN) {
    int node = blockIdx.x * 8 + (threadIdx.x >> 5);
    int c = threadIdx.x & 31;
    if (node >= nN) return;
    float rs_o = rsqrtf(fmaxf((float)cnt_src[node], 1.0f));
    if (c == 0) {
        rs_out[node] = rs_o;
        rs_in[node] = rsqrtf(fmaxf((float)cnt_dst[node], 1.0f));
    }
    if (c == 1) cursor[node] = off[node];
    float4 v = x[(size_t)node * 32 + c];
    v.x *= rs_o; v.y *= rs_o; v.z *= rs_o; v.w *= rs_o;
    xs[(size_t)node * 32 + c] = v;
}

// ---------------- scatter edges into CSR (sorted by dst) ----------------
// cursor pre-initialized to off[] -> atomic returns absolute position
__global__ void scatter_kernel(const int* __restrict__ src, const int* __restrict__ dst,
                               int* __restrict__ cursor, int* __restrict__ csr_src, int nE) {
    int e = blockIdx.x * blockDim.x + threadIdx.x;
    if (e < nE) {
        int pos = atomicAdd(&cursor[dst[e]], 1);
        csr_src[pos] = src[e];
    }
}

// ---------------- gather aggregation (pure row-sum, 2-way unrolled) ----------------
__global__ void gather_kernel(const float4* __restrict__ xin, const int* __restrict__ off,
                              const int* __restrict__ csr_src, float4* __restrict__ msg, int nN) {
    int node = blockIdx.x * 8 + (threadIdx.x >> 5);
    int c = threadIdx.x & 31;
    if (node >= nN) return;
    int beg = off[node], end = off[node + 1];
    float4 a0 = make_float4(0.f, 0.f, 0.f, 0.f);
    float4 a1 = make_float4(0.f, 0.f, 0.f, 0.f);
    int e = beg;
    for (; e + 1 < end; e += 2) {
        int s0 = csr_src[e];
        int s1 = csr_src[e + 1];
        float4 v0 = xin[(size_t)s0 * 32 + c];
        float4 v1 = xin[(size_t)s1 * 32 + c];
        a0.x += v0.x; a0.y += v0.y; a0.z += v0.z; a0.w += v0.w;
        a1.x += v1.x; a1.y += v1.y; a1.z += v1.z; a1.w += v1.w;
    }
    if (e < end) {
        int s0 = csr_src[e];
        float4 v0 = xin[(size_t)s0 * 32 + c];
        a0.x += v0.x; a0.y += v0.y; a0.z += v0.z; a0.w += v0.w;
    }
    a0.x += a1.x; a0.y += a1.y; a0.z += a1.z; a0.w += a1.w;
    msg[(size_t)node * 32 + c] = a0;
}

// ---------------- per-node dense layer ----------------
template <bool RELU_OUTSCALE>
__global__ void gemm_kernel(const float* __restrict__ msg, const float* __restrict__ rs_in,
                            const float* __restrict__ rs_out, const float* __restrict__ W,
                            const float* __restrict__ bias, float* __restrict__ out, int nN) {
    __shared__ float s[NB * D];
    int tid = threadIdx.x;  // 0..127
    int n0 = blockIdx.x * NB;
#pragma unroll
    for (int n = 0; n < NB; n++) {
        int node = n0 + n;
        s[n * D + tid] = (node < nN) ? msg[(size_t)node * D + tid] * rs_in[node] : 0.0f;
    }
    __syncthreads();
    float acc[NB];
#pragma unroll
    for (int n = 0; n < NB; n++) acc[n] = 0.0f;
    for (int k = 0; k < D; k++) {
        float w = W[k * D + tid];
#pragma unroll
        for (int n = 0; n < NB; n++) acc[n] += s[n * D + k] * w;
    }
    float bj = bias[tid];
#pragma unroll
    for (int n = 0; n < NB; n++) {
        int node = n0 + n;
        if (node >= nN) break;
        float v = acc[n] + bj;
        if (RELU_OUTSCALE) v = fmaxf(v, 0.0f) * rs_out[node];
        out[(size_t)node * D + tid] = v;
    }
}

extern "C" void kernel_launch(void* const* d_in, const int* in_sizes, int n_in,
                              void* d_out, int out_size, void* d_ws, size_t ws_size,
                              hipStream_t stream) {
    const float* x   = (const float*)d_in[0];
    const int*   src = (const int*)d_in[1];
    const int*   dst = (const int*)d_in[2];
    const float* W1  = (const float*)d_in[3];
    const float* b1  = (const float*)d_in[4];
    const float* W2  = (const float*)d_in[5];
    const float* b2  = (const float*)d_in[6];
    float* out = (float*)d_out;

    // workspace layout (xs aliases hs: xs dead before hs is written)
    char* ws = (char*)d_ws;
    int*   cnt_src = (int*)ws;                         ws += N_NODES * sizeof(int);
    int*   cnt_dst = (int*)ws;                         ws += N_NODES * sizeof(int);
    int*   csr_off = (int*)ws;                         ws += (N_NODES + 1) * sizeof(int);
    int*   cursor  = (int*)ws;                         ws += N_NODES * sizeof(int);
    int*   csr_src = (int*)ws;                         ws += N_EDGES * sizeof(int);
    float* rs_out  = (float*)ws;                       ws += N_NODES * sizeof(float);
    float* rs_in   = (float*)ws;                       ws += N_NODES * sizeof(float);
    float* msg     = (float*)ws;                       ws += (size_t)N_NODES * D * sizeof(float);
    float* xs      = (float*)ws;                       // aliased with hs
    float* hs      = xs;

    // zero the two histograms (adjacent -> one memset)
    hipMemsetAsync(cnt_src, 0, 2 * N_NODES * sizeof(int), stream);

    // histograms (deg_out == cnt_src, deg_in == cnt_dst)
    deg_kernel<<<(N_EDGES + 255) / 256, 256, 0, stream>>>(src, dst, cnt_src, cnt_dst, N_EDGES);

    // CSR offsets from cnt_dst
    scan_kernel<<<1, SCAN_T, 0, stream>>>(cnt_dst, csr_off, N_NODES);

    // rs arrays + cursor=off + xs = x * rs_out
    prescale_kernel<<<(N_NODES + 7) / 8, 256, 0, stream>>>((const float4*)x, cnt_src, cnt_dst,
                                                           csr_off, rs_out, rs_in, cursor,
                                                           (float4*)xs, N_NODES);

    // CSR column build
    scatter_kernel<<<(N_EDGES + 255) / 256, 256, 0, stream>>>(src, dst, cursor, csr_src, N_EDGES);

    // layer 1 aggregation: msg[n] = sum xs[s]
    gather_kernel<<<(N_NODES + 7) / 8, 256, 0, stream>>>((const float4*)xs, csr_off, csr_src,
                                                         (float4*)msg, N_NODES);

    // layer 1 dense: hs = relu((msg * rs_in) @ W1 + b1) * rs_out  (pre-scaled for next agg)
    gemm_kernel<true><<<(N_NODES + NB - 1) / NB, D, 0, stream>>>(msg, rs_in, rs_out, W1, b1, hs, N_NODES);

    // layer 2 aggregation: msg[n] = sum hs[s]
    gather_kernel<<<(N_NODES + 7) / 8, 256, 0, stream>>>((const float4*)hs, csr_off, csr_src,
                                                         (float4*)msg, N_NODES);

    // layer 2 dense: out = (msg * rs_in) @ W2 + b2
    gemm_kernel<false><<<(N_NODES + NB - 1) / NB, D, 0, stream>>>(msg, rs_in, nullptr, W2, b2, out, N_NODES);
}

// Round 4
// 434.119 us; speedup vs baseline: 6.6914x; 1.1455x over previous
//
#include <hip/hip_runtime.h>

#define N_NODES 50000
#define N_EDGES 800000
#define D 128
#define NB 16       // nodes per GEMM block
#define SCAN_B 256
#define N_SBLK ((N_NODES + SCAN_B - 1) / SCAN_B)  // 196

// ---------------- degree histograms (2 int atomics / edge) ----------------
__global__ void deg_kernel(const int* __restrict__ src, const int* __restrict__ dst,
                           int* __restrict__ cnt_src, int* __restrict__ cnt_dst, int nE) {
    int e = blockIdx.x * blockDim.x + threadIdx.x;
    if (e < nE) {
        atomicAdd(&cnt_src[src[e]], 1);
        atomicAdd(&cnt_dst[dst[e]], 1);
    }
}

// ---------------- hierarchical scan, step 1: per-block sums ----------------
__global__ void scan_sum_kernel(const int* __restrict__ cnt, int* __restrict__ blkSum, int n) {
    __shared__ int tmp[SCAN_B];
    int t = threadIdx.x;
    int i = blockIdx.x * SCAN_B + t;
    tmp[t] = (i < n) ? cnt[i] : 0;
    __syncthreads();
    for (int d = 128; d > 0; d >>= 1) {
        if (t < d) tmp[t] += tmp[t + d];
        __syncthreads();
    }
    if (t == 0) blkSum[blockIdx.x] = tmp[0];
}

// ---------------- hierarchical scan, step 2: exclusive offsets ----------------
__global__ void scan_off_kernel(const int* __restrict__ cnt, const int* __restrict__ blkSum,
                                int* __restrict__ off, int n, int nBlk) {
    __shared__ int bs[SCAN_B];
    __shared__ int tmp[SCAN_B];
    int t = threadIdx.x;
    bs[t] = (t < nBlk) ? blkSum[t] : 0;
    __syncthreads();
    for (int d = 1; d < SCAN_B; d <<= 1) {
        int a = (t >= d) ? bs[t - d] : 0;
        __syncthreads();
        bs[t] += a;
        __syncthreads();
    }
    int base = (blockIdx.x > 0) ? bs[blockIdx.x - 1] : 0;
    int i = blockIdx.x * SCAN_B + t;
    int v = (i < n) ? cnt[i] : 0;
    tmp[t] = v;
    __syncthreads();
    for (int d = 1; d < SCAN_B; d <<= 1) {
        int a = (t >= d) ? tmp[t - d] : 0;
        __syncthreads();
        tmp[t] += a;
        __syncthreads();
    }
    if (i < n) off[i] = base + tmp[t] - v;   // exclusive prefix
    if (i == n - 1) off[n] = base + tmp[t];  // total
}

// ---------------- fused: rs arrays, cursor init, xs = x * rs_out ----------------
__global__ void prescale_kernel(const float4* __restrict__ x, const int* __restrict__ cnt_src,
                                const int* __restrict__ cnt_dst, const int* __restrict__ off,
                                float* __restrict__ rs_out, float* __restrict__ rs_in,
                                int* __restrict__ cursor, float4* __restrict__ xs, int nN) {
    int node = blockIdx.x * 8 + (threadIdx.x >> 5);
    int c = threadIdx.x & 31;
    if (node >= nN) return;
    float rs_o = rsqrtf(fmaxf((float)cnt_src[node], 1.0f));
    if (c == 0) {
        rs_out[node] = rs_o;
        rs_in[node] = rsqrtf(fmaxf((float)cnt_dst[node], 1.0f));
    }
    if (c == 1) cursor[node] = off[node];
    float4 v = x[(size_t)node * 32 + c];
    v.x *= rs_o; v.y *= rs_o; v.z *= rs_o; v.w *= rs_o;
    xs[(size_t)node * 32 + c] = v;
}

// ---------------- scatter edges into CSR (sorted by dst) ----------------
__global__ void scatter_kernel(const int* __restrict__ src, const int* __restrict__ dst,
                               int* __restrict__ cursor, int* __restrict__ csr_src, int nE) {
    int e = blockIdx.x * blockDim.x + threadIdx.x;
    if (e < nE) {
        int pos = atomicAdd(&cursor[dst[e]], 1);
        csr_src[pos] = src[e];
    }
}

// ---------------- gather aggregation (pure row-sum, 2-way unrolled) ----------------
__global__ void gather_kernel(const float4* __restrict__ xin, const int* __restrict__ off,
                              const int* __restrict__ csr_src, float4* __restrict__ msg, int nN) {
    int node = blockIdx.x * 8 + (threadIdx.x >> 5);
    int c = threadIdx.x & 31;
    if (node >= nN) return;
    int beg = off[node], end = off[node + 1];
    float4 a0 = make_float4(0.f, 0.f, 0.f, 0.f);
    float4 a1 = make_float4(0.f, 0.f, 0.f, 0.f);
    int e = beg;
    for (; e + 1 < end; e += 2) {
        int s0 = csr_src[e];
        int s1 = csr_src[e + 1];
        float4 v0 = xin[(size_t)s0 * 32 + c];
        float4 v1 = xin[(size_t)s1 * 32 + c];
        a0.x += v0.x; a0.y += v0.y; a0.z += v0.z; a0.w += v0.w;
        a1.x += v1.x; a1.y += v1.y; a1.z += v1.z; a1.w += v1.w;
    }
    if (e < end) {
        int s0 = csr_src[e];
        float4 v0 = xin[(size_t)s0 * 32 + c];
        a0.x += v0.x; a0.y += v0.y; a0.z += v0.z; a0.w += v0.w;
    }
    a0.x += a1.x; a0.y += a1.y; a0.z += a1.z; a0.w += a1.w;
    msg[(size_t)node * 32 + c] = a0;
}

// ---------------- per-node dense layer (float4 LDS tile, k unrolled x4) ----------------
template <bool RELU_OUTSCALE>
__global__ void gemm_kernel(const float4* __restrict__ msg4, const float* __restrict__ rs_in,
                            const float* __restrict__ rs_out, const float* __restrict__ W,
                            const float* __restrict__ bias, float* __restrict__ out, int nN) {
    __shared__ float4 sv[NB * 32];  // 16 nodes x 128 floats
    int tid = threadIdx.x;  // 0..127
    int n0 = blockIdx.x * NB;
    // stage: 512 float4 elems by 128 threads (4 iters), coalesced
#pragma unroll
    for (int it = 0; it < 4; it++) {
        int idx = it * 128 + tid;
        int node = n0 + (idx >> 5);
        int c = idx & 31;
        float4 v = make_float4(0.f, 0.f, 0.f, 0.f);
        if (node < nN) {
            v = msg4[(size_t)node * 32 + c];
            float r = rs_in[node];
            v.x *= r; v.y *= r; v.z *= r; v.w *= r;
        }
        sv[idx] = v;
    }
    __syncthreads();
    float acc[NB];
#pragma unroll
    for (int n = 0; n < NB; n++) acc[n] = 0.0f;
    for (int k4 = 0; k4 < 32; k4++) {
        int k = k4 * 4;
        float w0 = W[(k + 0) * D + tid];
        float w1 = W[(k + 1) * D + tid];
        float w2 = W[(k + 2) * D + tid];
        float w3 = W[(k + 3) * D + tid];
#pragma unroll
        for (int n = 0; n < NB; n++) {
            float4 s4 = sv[n * 32 + k4];
            acc[n] += s4.x * w0 + s4.y * w1 + s4.z * w2 + s4.w * w3;
        }
    }
    float bj = bias[tid];
#pragma unroll
    for (int n = 0; n < NB; n++) {
        int node = n0 + n;
        if (node >= nN) break;
        float v = acc[n] + bj;
        if (RELU_OUTSCALE) v = fmaxf(v, 0.0f) * rs_out[node];
        out[(size_t)node * D + tid] = v;
    }
}

static inline size_t align16(size_t x) { return (x + 15) & ~(size_t)15; }

extern "C" void kernel_launch(void* const* d_in, const int* in_sizes, int n_in,
                              void* d_out, int out_size, void* d_ws, size_t ws_size,
                              hipStream_t stream) {
    const float* x   = (const float*)d_in[0];
    const int*   src = (const int*)d_in[1];
    const int*   dst = (const int*)d_in[2];
    const float* W1  = (const float*)d_in[3];
    const float* b1  = (const float*)d_in[4];
    const float* W2  = (const float*)d_in[5];
    const float* b2  = (const float*)d_in[6];
    float* out = (float*)d_out;

    // workspace layout, all regions 16B-aligned (xs aliases hs: xs dead before hs written)
    char* ws = (char*)d_ws;
    int*   cnt_src = (int*)ws;    ws += align16(N_NODES * sizeof(int));
    int*   cnt_dst = (int*)ws;    ws += align16(N_NODES * sizeof(int));
    int*   csr_off = (int*)ws;    ws += align16((N_NODES + 1) * sizeof(int));
    int*   cursor  = (int*)ws;    ws += align16(N_NODES * sizeof(int));
    int*   blkSum  = (int*)ws;    ws += align16(N_SBLK * sizeof(int));
    int*   csr_src = (int*)ws;    ws += align16(N_EDGES * sizeof(int));
    float* rs_out  = (float*)ws;  ws += align16(N_NODES * sizeof(float));
    float* rs_in   = (float*)ws;  ws += align16(N_NODES * sizeof(float));
    float* msg     = (float*)ws;  ws += align16((size_t)N_NODES * D * sizeof(float));
    float* xs      = (float*)ws;  // aliased with hs
    float* hs      = xs;

    // zero the two adjacent histograms in one memset
    hipMemsetAsync(cnt_src, 0, 2 * align16(N_NODES * sizeof(int)), stream);

    // histograms (deg_out == cnt_src, deg_in == cnt_dst)
    deg_kernel<<<(N_EDGES + 255) / 256, 256, 0, stream>>>(src, dst, cnt_src, cnt_dst, N_EDGES);

    // hierarchical CSR-offset scan of cnt_dst
    scan_sum_kernel<<<N_SBLK, SCAN_B, 0, stream>>>(cnt_dst, blkSum, N_NODES);
    scan_off_kernel<<<N_SBLK, SCAN_B, 0, stream>>>(cnt_dst, blkSum, csr_off, N_NODES, N_SBLK);

    // rs arrays + cursor=off + xs = x * rs_out
    prescale_kernel<<<(N_NODES + 7) / 8, 256, 0, stream>>>((const float4*)x, cnt_src, cnt_dst,
                                                           csr_off, rs_out, rs_in, cursor,
                                                           (float4*)xs, N_NODES);

    // CSR column build
    scatter_kernel<<<(N_EDGES + 255) / 256, 256, 0, stream>>>(src, dst, cursor, csr_src, N_EDGES);

    // layer 1 aggregation: msg[n] = sum xs[s]
    gather_kernel<<<(N_NODES + 7) / 8, 256, 0, stream>>>((const float4*)xs, csr_off, csr_src,
                                                         (float4*)msg, N_NODES);

    // layer 1 dense: hs = relu((msg * rs_in) @ W1 + b1) * rs_out
    gemm_kernel<true><<<(N_NODES + NB - 1) / NB, D, 0, stream>>>((const float4*)msg, rs_in, rs_out,
                                                                 W1, b1, hs, N_NODES);

    // layer 2 aggregation: msg[n] = sum hs[s]
    gather_kernel<<<(N_NODES + 7) / 8, 256, 0, stream>>>((const float4*)hs, csr_off, csr_src,
                                                         (float4*)msg, N_NODES);

    // layer 2 dense: out = (msg * rs_in) @ W2 + b2
    gemm_kernel<false><<<(N_NODES + NB - 1) / NB, D, 0, stream>>>((const float4*)msg, rs_in, nullptr,
                                                                  W2, b2, out, N_NODES);
}